// Round 8
// baseline (481.728 us; speedup 1.0000x reference)
//
#include <hip/hip_runtime.h>

#define NN 50000
#define NE 800000
#define D 64
#define SCAN_B 1024
#define NB ((NN + SCAN_B - 1) / SCAN_B)   // 49 scan blocks
#define TILES 5
#define EPB (64 * TILES)                   // 320 edges/block (4 waves x 80), grid 2500

typedef __attribute__((ext_vector_type(8))) short bf16x8;
typedef __attribute__((ext_vector_type(4))) float f32x4;

__device__ __forceinline__ float lrelu(float x) { return x >= 0.0f ? x : 0.2f * x; }

__device__ __forceinline__ unsigned short f2bf(float f) {
    unsigned int x = __float_as_uint(f);
    unsigned int r = (x + 0x7fffu + ((x >> 16) & 1u)) >> 16;   // RNE
    return (unsigned short)r;
}

// per-wave LDS fence: all my outstanding LDS ops done, nothing crosses
__device__ __forceinline__ void wave_lds_fence() {
    asm volatile("s_waitcnt lgkmcnt(0)" ::: "memory");
    __builtin_amdgcn_sched_barrier(0);
}

// ---------- fused prep: h->bf16, all 4 weights ->bf16^T, degree count ----------
__global__ __launch_bounds__(256) void prep_count(const float* __restrict__ h,
                                                  unsigned short* __restrict__ hb,
                                                  const int* __restrict__ ei,
                                                  int* __restrict__ counts,
                                                  const float* __restrict__ w1e,
                                                  const float* __restrict__ w2e,
                                                  const float* __restrict__ w1n,
                                                  const float* __restrict__ w2n,
                                                  unsigned short* __restrict__ w1t,
                                                  unsigned short* __restrict__ w2t,
                                                  unsigned short* __restrict__ w1nt,
                                                  unsigned short* __restrict__ w2nt)
{
    int i = blockIdx.x * 256 + threadIdx.x;   // 800000 threads exactly
    float4 v = ((const float4*)h)[i];         // NN*16 == NE exactly
    ushort4 o;
    o.x = f2bf(v.x); o.y = f2bf(v.y); o.z = f2bf(v.z); o.w = f2bf(v.w);
    ((ushort4*)hb)[i] = o;
    atomicAdd(&counts[ei[i]], 1);
    if (i < 8192) {                            // w1t[j][k] = w1e[k][j]
        int j = i >> 7, k = i & 127;
        w1t[i] = f2bf(w1e[k * 64 + j]);
    } else if (i < 12288) {                    // w2t[j][k] = w2e[k][j]
        int t2 = i - 8192;
        int j = t2 >> 6, k = t2 & 63;
        w2t[t2] = f2bf(w2e[k * 64 + j]);
    } else if (i < 20480) {                    // w1nt[j][k] = w1n[k][j]
        int t3 = i - 12288;
        int j = t3 >> 7, k = t3 & 127;
        w1nt[t3] = f2bf(w1n[k * 64 + j]);
    } else if (i < 24576) {                    // w2nt[j][k] = w2n[k][j]
        int t4 = i - 20480;
        int j = t4 >> 6, k = t4 & 63;
        w2nt[t4] = f2bf(w2n[k * 64 + j]);
    }
}

// ---------- CSR build ----------
__global__ __launch_bounds__(SCAN_B) void scan_block_kernel(const int* __restrict__ counts,
                                                            int* __restrict__ offs,
                                                            int* __restrict__ bsums)
{
    int i = blockIdx.x * SCAN_B + threadIdx.x;
    int v = (i < NN) ? counts[i] : 0;
    int lane = threadIdx.x & 63;
    int wid = threadIdx.x >> 6;
    int x = v;
#pragma unroll
    for (int d = 1; d < 64; d <<= 1) {
        int y = __shfl_up(x, d);
        if (lane >= d) x += y;
    }
    __shared__ int wsum[16];
    if (lane == 63) wsum[wid] = x;
    __syncthreads();
    if (wid == 0) {
        int s = (lane < 16) ? wsum[lane] : 0;
#pragma unroll
        for (int d = 1; d < 16; d <<= 1) {
            int y = __shfl_up(s, d);
            if (lane >= d) s += y;
        }
        if (lane < 16) wsum[lane] = s;
    }
    __syncthreads();
    int woff = (wid == 0) ? 0 : wsum[wid - 1];
    int excl = woff + x - v;
    if (i < NN) offs[i] = excl;
    if (threadIdx.x == 0) bsums[blockIdx.x] = wsum[15];
}

__global__ void scan_top_kernel(int* __restrict__ bsums)
{
    if (threadIdx.x == 0 && blockIdx.x == 0) {
        int run = 0;
        for (int b = 0; b < NB; b++) { int t = bsums[b]; bsums[b] = run; run += t; }
    }
}

__global__ __launch_bounds__(SCAN_B) void add_back_kernel(int* __restrict__ offs,
                                                          const int* __restrict__ bsums,
                                                          int* __restrict__ cursor)
{
    int i = blockIdx.x * SCAN_B + threadIdx.x;
    if (i < NN) {
        int o = offs[i] + bsums[blockIdx.x];
        offs[i] = o;
        cursor[i] = o;
    }
}

__global__ __launch_bounds__(256) void scatter_kernel(const int* __restrict__ ei,
                                                      int* __restrict__ cursor,
                                                      int* __restrict__ csr,
                                                      int* __restrict__ rowpos)
{
    int e = blockIdx.x * 256 + threadIdx.x;
    if (e < NE) {
        int r = ei[e];
        int pos = atomicAdd(&cursor[r], 1);
        csr[pos] = e;
        rowpos[pos] = r;
    }
}

// ---------- edge MLP: wave-independent 16-edge tiles, zero block barriers ----------
// Wave wv handles pos [blk*EPB + wv*80, +80) in 5 tiles of 16 (CSR order, rows sorted).
// Per tile: A[16][128]bf16 (wave-private, swizzled) -> 16 MFMA -> M[16][64] -> 8 MFMA
// -> out f32[16][64] overlaying A -> contiguous row stores + segmented agg scan.
__global__ __launch_bounds__(256, 3) void egnn_edge_mfma(
    const unsigned short* __restrict__ hb, const float* __restrict__ coord,
    const int* __restrict__ ei,
    const int* __restrict__ csr, const int* __restrict__ rowpos,
    const unsigned short* __restrict__ w1t, const float* __restrict__ b1e,
    const float* __restrict__ w1e,   // fp32, for radial row w1e[128][j]
    const unsigned short* __restrict__ w2t, const float* __restrict__ b2e,
    float* __restrict__ edge_feat, float* __restrict__ agg)
{
    __shared__ unsigned short Awork[4][16 * 128];   // 4 KB/wave: A bf16, then out f32 overlay
    __shared__ unsigned short Mw[4][16 * 64];       // 2 KB/wave
    __shared__ float rad_lds[4][16];
    __shared__ int rl_lds[4][16];

    const int t = threadIdx.x;
    // bijective XCD swizzle (m204): nwg=2500 = 8*312+4
    const int orig = blockIdx.x;
    const int xcd = orig & 7, rest = orig >> 3;
    const int blk = (xcd < 4 ? xcd * 313 : 4 * 313 + (xcd - 4) * 312) + rest;

    const int lane = t & 63, wv = t >> 6;
    const int lo = lane & 15, hi = lane >> 4;

    // per-wave B1 fragments (all 4 col-tiles) + bias/radial weights
    bf16x8 b1f[4][4];
#pragma unroll
    for (int kc = 0; kc < 4; kc++)
#pragma unroll
        for (int ct = 0; ct < 4; ct++)
            b1f[kc][ct] = *(const bf16x8*)(w1t + (ct * 16 + lo) * 128 + kc * 32 + hi * 8);
    float bj1[4], wl1[4], bj2[4];
#pragma unroll
    for (int ct = 0; ct < 4; ct++) {
        bj1[ct] = b1e[ct * 16 + lo];
        wl1[ct] = w1e[128 * 64 + ct * 16 + lo];
        bj2[ct] = b2e[ct * 16 + lo];
    }

    char* abase = (char*)Awork[wv];
    char* mbase = (char*)Mw[wv];

    const int ep = lane >> 2, seg = lane & 3;   // staging: 4 lanes per edge, 64B each
    const int sw = (ep & 7) << 4;
    const int rbase = ep * 256 + seg * 64;
    const int pbase = blk * EPB + wv * (16 * TILES);

    uint4 pre[4];
    float cr0, cr1, cr2, cc0, cc1, cc2;
    int rowC, colC, rowN, colN;

    {   // prologue: tile0 data + tile1 ids
        int p0 = pbase + ep;
        int e0 = csr[p0];
        rowC = rowpos[p0];
        colC = ei[NE + e0];
        int nd = (seg < 2) ? rowC : colC;
        const uint4* src = (const uint4*)(hb + (size_t)nd * 64 + (seg & 1) * 32);
#pragma unroll
        for (int c = 0; c < 4; c++) pre[c] = src[c];
        if (seg == 0) {
            cr0 = coord[rowC * 3 + 0]; cr1 = coord[rowC * 3 + 1]; cr2 = coord[rowC * 3 + 2];
            cc0 = coord[colC * 3 + 0]; cc1 = coord[colC * 3 + 1]; cc2 = coord[colC * 3 + 2];
        }
        int p1 = p0 + 16;
        int e1 = csr[p1];
        rowN = rowpos[p1];
        colN = ei[NE + e1];
    }

#pragma unroll
    for (int tl = 0; tl < TILES; tl++) {
        // ---- 1. stage current tile (prior tile's LDS reads drained first) ----
        wave_lds_fence();
#pragma unroll
        for (int c = 0; c < 4; c++)
            *(uint4*)(abase + ((rbase + c * 16) ^ sw)) = pre[c];
        if (seg == 0) {
            float dx = cr0 - cc0, dy = cr1 - cc1, dz = cr2 - cc2;
            rad_lds[wv][ep] = dx * dx + dy * dy + dz * dz;
        }
        if (seg == 1) rl_lds[wv][ep] = rowC;

        // ---- 2. kick next tile's gathers (hidden under MFMA) ----
        if (tl + 1 < TILES) {
            int nd = (seg < 2) ? rowN : colN;
            const uint4* src = (const uint4*)(hb + (size_t)nd * 64 + (seg & 1) * 32);
            int rsave = rowN, csave = colN;
            if (tl + 2 < TILES) {
                int p2 = pbase + (tl + 2) * 16 + ep;
                int e2 = csr[p2];
                rowN = rowpos[p2];
                colN = ei[NE + e2];
            }
#pragma unroll
            for (int c = 0; c < 4; c++) pre[c] = src[c];
            if (seg == 0) {
                cr0 = coord[rsave * 3 + 0]; cr1 = coord[rsave * 3 + 1]; cr2 = coord[rsave * 3 + 2];
                cc0 = coord[csave * 3 + 0]; cc1 = coord[csave * 3 + 1]; cc2 = coord[csave * 3 + 2];
            }
            rowC = rsave; colC = csave;
        }
        // b2 frags for this tile (L1-resident, short-lived regs)
        bf16x8 b2f[2][4];
#pragma unroll
        for (int kc = 0; kc < 2; kc++)
#pragma unroll
            for (int ct = 0; ct < 4; ct++)
                b2f[kc][ct] = *(const bf16x8*)(w2t + (ct * 16 + lo) * 64 + kc * 32 + hi * 8);

        // ---- 3. layer 1 ----
        wave_lds_fence();                     // A + rad + rl staged
        float radv[4];
#pragma unroll
        for (int r = 0; r < 4; r++) radv[r] = rad_lds[wv][hi * 4 + r];
        f32x4 acc[4];
#pragma unroll
        for (int ct = 0; ct < 4; ct++)
#pragma unroll
            for (int r = 0; r < 4; r++) acc[ct][r] = fmaf(radv[r], wl1[ct], bj1[ct]);
#pragma unroll
        for (int kc = 0; kc < 4; kc++) {
            bf16x8 a = *(bf16x8*)(abase + ((lo * 256 + kc * 64 + hi * 16) ^ ((lo & 7) << 4)));
#pragma unroll
            for (int ct = 0; ct < 4; ct++)
                acc[ct] = __builtin_amdgcn_mfma_f32_16x16x32_bf16(a, b1f[kc][ct], acc[ct], 0, 0, 0);
        }

        // ---- 4. M stage + layer 2 ----
#pragma unroll
        for (int ct = 0; ct < 4; ct++)
#pragma unroll
            for (int r = 0; r < 4; r++) {
                int row = hi * 4 + r;
                *(unsigned short*)(mbase + ((row * 128 + (ct * 16 + lo) * 2) ^ ((row & 7) << 4))) =
                    f2bf(lrelu(acc[ct][r]));
            }
        wave_lds_fence();
        f32x4 acc2[4];
#pragma unroll
        for (int ct = 0; ct < 4; ct++)
#pragma unroll
            for (int r = 0; r < 4; r++) acc2[ct][r] = bj2[ct];
#pragma unroll
        for (int kc = 0; kc < 2; kc++) {
            bf16x8 a = *(bf16x8*)(mbase + ((lo * 128 + kc * 64 + hi * 16) ^ ((lo & 7) << 4)));
#pragma unroll
            for (int ct = 0; ct < 4; ct++)
                acc2[ct] = __builtin_amdgcn_mfma_f32_16x16x32_bf16(a, b2f[kc][ct], acc2[ct], 0, 0, 0);
        }

        // ---- 5. out-tile f32[16][64] overlaying A ----
#pragma unroll
        for (int ct = 0; ct < 4; ct++)
#pragma unroll
            for (int r = 0; r < 4; r++) {
                int row = hi * 4 + r;
                *(float*)(abase + ((row * 256 + (ct * 16 + lo) * 4) ^ ((row & 7) << 4))) =
                    lrelu(acc2[ct][r]);
            }
        wave_lds_fence();

        // ---- 6a. edge_feat stores: edge-major, 4x256B contiguous per wave-op ----
        {
            int e4 = lane >> 4;        // 0..3
            int ch = lane & 15;        // 16B chunk
#pragma unroll
            for (int o = 0; o < 4; o++) {
                int eidx = o * 4 + e4;
                int ee = csr[pbase + tl * 16 + eidx];
                uint4 v = *(uint4*)(abase + ((eidx * 256 + ch * 16) ^ ((eidx & 7) << 4)));
                *(uint4*)(edge_feat + (size_t)ee * 64 + ch * 4) = v;
            }
        }
        // ---- 6b. segmented agg scan over this wave's 16 sorted pos ----
        {
            int cur = rl_lds[wv][0];
            float s = *(float*)(abase + ((0 * 256 + lane * 4) ^ 0));
#pragma unroll
            for (int ii = 1; ii < 16; ii++) {
                int r = rl_lds[wv][ii];          // wave-uniform
                float v = *(float*)(abase + ((ii * 256 + lane * 4) ^ ((ii & 7) << 4)));
                if (r != cur) {
                    atomicAdd(&agg[(size_t)cur * 64 + lane], s);
                    s = v; cur = r;
                } else {
                    s += v;
                }
            }
            atomicAdd(&agg[(size_t)cur * 64 + lane], s);
        }
    }
}

// ---------- node MLP (MFMA): streamed agg read, no gather ----------
__global__ __launch_bounds__(256) void agg_node_mfma(
    const unsigned short* __restrict__ hb, const float* __restrict__ h,
    const float* __restrict__ coord, const float* __restrict__ agg,
    const unsigned short* __restrict__ w1nt, const float* __restrict__ b1n,
    const unsigned short* __restrict__ w2nt, const float* __restrict__ b2n,
    float* __restrict__ h_out, float* __restrict__ coord_out)
{
    __shared__ unsigned short Alds[64 * 128];   // [hb | agg_bf16], swizzled
    __shared__ unsigned short Mlds[64 * 64];

    const int t = threadIdx.x, blk = blockIdx.x;
    const int lane = t & 63, wv = t >> 6;
    const int lo = lane & 15, hi = lane >> 4;
    const int nb = blk * 64;
    char* abase = (char*)Alds;
    char* mbase = (char*)Mlds;

    bf16x8 b1f[4], b2f[2];
#pragma unroll
    for (int kc = 0; kc < 4; kc++)
        b1f[kc] = *(const bf16x8*)(w1nt + (wv * 16 + lo) * 128 + kc * 32 + hi * 8);
#pragma unroll
    for (int kc = 0; kc < 2; kc++)
        b2f[kc] = *(const bf16x8*)(w2nt + (wv * 16 + lo) * 64 + kc * 32 + hi * 8);
    const float bj1 = b1n[wv * 16 + lo];
    const float bj2 = b2n[wv * 16 + lo];

    {   // stage hb rows -> A cols 0..63
        int row = t >> 2, seg = t & 3;
        int n = min(nb + row, NN - 1);
        const uint4* src = (const uint4*)(hb + (size_t)n * 64 + seg * 16);
        int base = row * 256 + seg * 32;
        int swr = (row & 7) << 4;
        uint4 v0 = src[0], v1 = src[1];
        *(uint4*)(abase + (base ^ swr)) = v0;
        *(uint4*)(abase + ((base + 16) ^ swr)) = v1;
    }
    {   // stage agg rows (fp32 -> bf16) -> A cols 64..127
        int row = t >> 2, seg = t & 3;
        int n = min(nb + row, NN - 1);
        const float4* asrc = (const float4*)(agg + (size_t)n * 64 + seg * 16);
        float4 a0 = asrc[0], a1 = asrc[1], a2 = asrc[2], a3 = asrc[3];
        unsigned int u0 = f2bf(a0.x) | ((unsigned)f2bf(a0.y) << 16);
        unsigned int u1 = f2bf(a0.z) | ((unsigned)f2bf(a0.w) << 16);
        unsigned int u2 = f2bf(a1.x) | ((unsigned)f2bf(a1.y) << 16);
        unsigned int u3 = f2bf(a1.z) | ((unsigned)f2bf(a1.w) << 16);
        unsigned int u4 = f2bf(a2.x) | ((unsigned)f2bf(a2.y) << 16);
        unsigned int u5 = f2bf(a2.z) | ((unsigned)f2bf(a2.w) << 16);
        unsigned int u6 = f2bf(a3.x) | ((unsigned)f2bf(a3.y) << 16);
        unsigned int u7 = f2bf(a3.z) | ((unsigned)f2bf(a3.w) << 16);
        int base = row * 256 + 128 + seg * 32;
        int swr = (row & 7) << 4;
        *(uint4*)(abase + (base ^ swr)) = make_uint4(u0, u1, u2, u3);
        *(uint4*)(abase + ((base + 16) ^ swr)) = make_uint4(u4, u5, u6, u7);
    }
    __syncthreads();

    f32x4 acc[4];
#pragma unroll
    for (int rt = 0; rt < 4; rt++) {
#pragma unroll
        for (int r = 0; r < 4; r++) acc[rt][r] = bj1;
    }
#pragma unroll
    for (int kc = 0; kc < 4; kc++) {
#pragma unroll
        for (int rt = 0; rt < 4; rt++) {
            int row = rt * 16 + lo;
            bf16x8 a = *(bf16x8*)(abase + ((row * 256 + kc * 64 + hi * 16) ^ ((row & 7) << 4)));
            acc[rt] = __builtin_amdgcn_mfma_f32_16x16x32_bf16(a, b1f[kc], acc[rt], 0, 0, 0);
        }
    }
#pragma unroll
    for (int rt = 0; rt < 4; rt++) {
#pragma unroll
        for (int r = 0; r < 4; r++) {
            int row = rt * 16 + hi * 4 + r;
            *(unsigned short*)(mbase + ((row * 128 + (wv * 16 + lo) * 2) ^ ((row & 7) << 4))) =
                f2bf(lrelu(acc[rt][r]));
        }
    }
    __syncthreads();

    f32x4 acc2[4];
#pragma unroll
    for (int rt = 0; rt < 4; rt++) {
#pragma unroll
        for (int r = 0; r < 4; r++) acc2[rt][r] = bj2;
    }
#pragma unroll
    for (int kc = 0; kc < 2; kc++) {
#pragma unroll
        for (int rt = 0; rt < 4; rt++) {
            int row = rt * 16 + lo;
            bf16x8 a = *(bf16x8*)(mbase + ((row * 128 + kc * 64 + hi * 16) ^ ((row & 7) << 4)));
            acc2[rt] = __builtin_amdgcn_mfma_f32_16x16x32_bf16(a, b2f[kc], acc2[rt], 0, 0, 0);
        }
    }
#pragma unroll
    for (int rt = 0; rt < 4; rt++) {
#pragma unroll
        for (int r = 0; r < 4; r++) {
            int row = rt * 16 + hi * 4 + r;
            int n = nb + row;
            if (n < NN) {
                int c = wv * 16 + lo;
                h_out[(size_t)n * 64 + c] = h[(size_t)n * 64 + c] + acc2[rt][r];
            }
        }
    }

    if (t < 192) {
        int idx = nb * 3 + t;
        if (idx < NN * 3) coord_out[idx] = coord[idx];
    }
}

extern "C" void kernel_launch(void* const* d_in, const int* in_sizes, int n_in,
                              void* d_out, int out_size, void* d_ws, size_t ws_size,
                              hipStream_t stream)
{
    const float* h     = (const float*)d_in[0];
    const float* coord = (const float*)d_in[1];
    const int*   ei    = (const int*)d_in[2];
    const float* w1e   = (const float*)d_in[3];
    const float* b1e   = (const float*)d_in[4];
    const float* w2e   = (const float*)d_in[5];
    const float* b2e   = (const float*)d_in[6];
    const float* w1n   = (const float*)d_in[7];
    const float* b1n   = (const float*)d_in[8];
    const float* w2n   = (const float*)d_in[9];
    const float* b2n   = (const float*)d_in[10];

    float* out       = (float*)d_out;
    float* h_out     = out;                         // [N, 64]
    float* coord_out = out + (size_t)NN * D;        // [N, 3]
    float* edge_feat = coord_out + (size_t)NN * 3;  // [E, 64]

    char* ws = (char*)d_ws;
    unsigned short* hb   = (unsigned short*)ws;  ws += sizeof(unsigned short) * (size_t)NN * D;  // 6.4 MB
    unsigned short* w1t  = (unsigned short*)ws;  ws += sizeof(unsigned short) * 64 * 128;
    unsigned short* w2t  = (unsigned short*)ws;  ws += sizeof(unsigned short) * 64 * 64;
    unsigned short* w1nt = (unsigned short*)ws;  ws += sizeof(unsigned short) * 64 * 128;
    unsigned short* w2nt = (unsigned short*)ws;  ws += sizeof(unsigned short) * 64 * 64;
    float* agg  = (float*)ws;                    ws += sizeof(float) * (size_t)NN * D;           // 12.8 MB
    int* counts = (int*)ws;                      ws += sizeof(int) * NN;
    int* offs   = (int*)ws;                      ws += sizeof(int) * NN;
    int* cursor = (int*)ws;                      ws += sizeof(int) * NN;
    int* bsums  = (int*)ws;                      ws += sizeof(int) * 64;
    int* csr    = (int*)ws;                      ws += sizeof(int) * NE;                         // 3.2 MB
    int* rowpos = (int*)ws;                      ws += sizeof(int) * NE;                         // 3.2 MB

    hipMemsetAsync(counts, 0, sizeof(int) * NN, stream);
    hipMemsetAsync(agg, 0, sizeof(float) * (size_t)NN * D, stream);

    prep_count<<<NE / 256, 256, 0, stream>>>(h, hb, ei, counts,
                                             w1e, w2e, w1n, w2n, w1t, w2t, w1nt, w2nt);

    scan_block_kernel<<<NB, SCAN_B, 0, stream>>>(counts, offs, bsums);
    scan_top_kernel<<<1, 64, 0, stream>>>(bsums);
    add_back_kernel<<<NB, SCAN_B, 0, stream>>>(offs, bsums, cursor);
    scatter_kernel<<<(NE + 255) / 256, 256, 0, stream>>>(ei, cursor, csr, rowpos);

    egnn_edge_mfma<<<NE / EPB, 256, 0, stream>>>(
        hb, coord, ei, csr, rowpos, w1t, b1e, w1e, w2t, b2e, edge_feat, agg);

    agg_node_mfma<<<(NN + 63) / 64, 256, 0, stream>>>(
        hb, h, coord, agg, w1nt, b1n, w2nt, b2n, h_out, coord_out);
}

// Round 9
// 257.272 us; speedup vs baseline: 1.8724x; 1.8724x over previous
//
#include <hip/hip_runtime.h>

#define NN 50000
#define NE 800000
#define D 64
#define SCAN_B 1024
#define NB ((NN + SCAN_B - 1) / SCAN_B)   // 49 scan blocks
#define TILES 5
#define EPB (64 * TILES)                   // 320 edges/block, grid 2500 exact

typedef __attribute__((ext_vector_type(8))) short bf16x8;
typedef __attribute__((ext_vector_type(4))) float f32x4;

__device__ __forceinline__ float lrelu(float x) { return x >= 0.0f ? x : 0.2f * x; }

__device__ __forceinline__ unsigned short f2bf(float f) {
    unsigned int x = __float_as_uint(f);
    unsigned int r = (x + 0x7fffu + ((x >> 16) & 1u)) >> 16;   // RNE
    return (unsigned short)r;
}

// ---------- fused prep: h->bf16, all 4 weights ->bf16^T, degree count ----------
__global__ __launch_bounds__(256) void prep_count(const float* __restrict__ h,
                                                  unsigned short* __restrict__ hb,
                                                  const int* __restrict__ ei,
                                                  int* __restrict__ counts,
                                                  const float* __restrict__ w1e,
                                                  const float* __restrict__ w2e,
                                                  const float* __restrict__ w1n,
                                                  const float* __restrict__ w2n,
                                                  unsigned short* __restrict__ w1t,
                                                  unsigned short* __restrict__ w2t,
                                                  unsigned short* __restrict__ w1nt,
                                                  unsigned short* __restrict__ w2nt)
{
    int i = blockIdx.x * 256 + threadIdx.x;   // 800000 threads exactly
    float4 v = ((const float4*)h)[i];         // NN*16 == NE exactly
    ushort4 o;
    o.x = f2bf(v.x); o.y = f2bf(v.y); o.z = f2bf(v.z); o.w = f2bf(v.w);
    ((ushort4*)hb)[i] = o;
    atomicAdd(&counts[ei[i]], 1);
    if (i < 8192) {                            // w1t[j][k] = w1e[k][j]
        int j = i >> 7, k = i & 127;
        w1t[i] = f2bf(w1e[k * 64 + j]);
    } else if (i < 12288) {                    // w2t[j][k] = w2e[k][j]
        int t2 = i - 8192;
        int j = t2 >> 6, k = t2 & 63;
        w2t[t2] = f2bf(w2e[k * 64 + j]);
    } else if (i < 20480) {                    // w1nt[j][k] = w1n[k][j]
        int t3 = i - 12288;
        int j = t3 >> 7, k = t3 & 127;
        w1nt[t3] = f2bf(w1n[k * 64 + j]);
    } else if (i < 24576) {                    // w2nt[j][k] = w2n[k][j]
        int t4 = i - 20480;
        int j = t4 >> 6, k = t4 & 63;
        w2nt[t4] = f2bf(w2n[k * 64 + j]);
    }
}

// ---------- CSR build ----------
__global__ __launch_bounds__(SCAN_B) void scan_block_kernel(const int* __restrict__ counts,
                                                            int* __restrict__ offs,
                                                            int* __restrict__ bsums)
{
    int i = blockIdx.x * SCAN_B + threadIdx.x;
    int v = (i < NN) ? counts[i] : 0;
    int lane = threadIdx.x & 63;
    int wid = threadIdx.x >> 6;
    int x = v;
#pragma unroll
    for (int d = 1; d < 64; d <<= 1) {
        int y = __shfl_up(x, d);
        if (lane >= d) x += y;
    }
    __shared__ int wsum[16];
    if (lane == 63) wsum[wid] = x;
    __syncthreads();
    if (wid == 0) {
        int s = (lane < 16) ? wsum[lane] : 0;
#pragma unroll
        for (int d = 1; d < 16; d <<= 1) {
            int y = __shfl_up(s, d);
            if (lane >= d) s += y;
        }
        if (lane < 16) wsum[lane] = s;
    }
    __syncthreads();
    int woff = (wid == 0) ? 0 : wsum[wid - 1];
    int excl = woff + x - v;
    if (i < NN) offs[i] = excl;
    if (threadIdx.x == 0) bsums[blockIdx.x] = wsum[15];
}

__global__ void scan_top_kernel(int* __restrict__ bsums)
{
    if (threadIdx.x == 0 && blockIdx.x == 0) {
        int run = 0;
        for (int b = 0; b < NB; b++) { int t = bsums[b]; bsums[b] = run; run += t; }
    }
}

__global__ __launch_bounds__(SCAN_B) void add_back_kernel(int* __restrict__ offs,
                                                          const int* __restrict__ bsums,
                                                          int* __restrict__ cursor)
{
    int i = blockIdx.x * SCAN_B + threadIdx.x;
    if (i < NN) {
        int o = offs[i] + bsums[blockIdx.x];
        offs[i] = o;
        cursor[i] = o;
    }
}

__global__ __launch_bounds__(256) void scatter_kernel(const int* __restrict__ ei,
                                                      int* __restrict__ cursor,
                                                      int* __restrict__ csr,
                                                      int* __restrict__ rowpos)
{
    int e = blockIdx.x * 256 + threadIdx.x;
    if (e < NE) {
        int r = ei[e];
        int pos = atomicAdd(&cursor[r], 1);
        csr[pos] = e;
        rowpos[pos] = r;
    }
}

// ---------- edge MLP: 4-wave cooperative, depth-2 pipeline, CSR order, fused agg ----------
// pos p = blk*EPB + tl*64 + ep; edge e = csr[p]; row = rowpos[p] (nondecreasing).
// Wave wv owns output col-stripe [wv*16,+16). All index/coord chains hoisted to prologue.
__global__ __launch_bounds__(256) void egnn_edge_mfma(
    const unsigned short* __restrict__ hb, const float* __restrict__ coord,
    const int* __restrict__ ei,
    const int* __restrict__ csr, const int* __restrict__ rowpos,
    const unsigned short* __restrict__ w1t, const float* __restrict__ b1e,
    const float* __restrict__ w1e,   // fp32, for radial row w1e[128][j]
    const unsigned short* __restrict__ w2t, const float* __restrict__ b2e,
    float* __restrict__ edge_feat, float* __restrict__ agg)
{
    __shared__ unsigned short Alds[64 * 128];   // 16 KB: A bf16 tile, then fp32 out overlay
    __shared__ unsigned short Mlds[64 * 64];    // 8 KB
    __shared__ float rad_lds[64];
    __shared__ int rl_lds[64];                  // row id per pos-slot
    __shared__ int el_lds[64];                  // edge id per pos-slot

    const int t = threadIdx.x, blk = blockIdx.x;
    const int lane = t & 63, wv = t >> 6;
    const int lo = lane & 15, hi = lane >> 4;

    // per-wave B stripes (24 VGPR resident)
    bf16x8 b1f[4], b2f[2];
#pragma unroll
    for (int kc = 0; kc < 4; kc++)
        b1f[kc] = *(const bf16x8*)(w1t + (wv * 16 + lo) * 128 + kc * 32 + hi * 8);
#pragma unroll
    for (int kc = 0; kc < 2; kc++)
        b2f[kc] = *(const bf16x8*)(w2t + (wv * 16 + lo) * 64 + kc * 32 + hi * 8);
    const float bj1 = b1e[wv * 16 + lo];
    const float wl1 = w1e[128 * 64 + wv * 16 + lo];
    const float bj2 = b2e[wv * 16 + lo];

    const int ep = t >> 2, seg = t & 3;   // staging: 4 threads per edge slot
    char* abase = (char*)Alds;
    char* mbase = (char*)Mlds;
    const int sw = (ep & 7) << 4;
    const int rbase = ep * 256 + seg * 64;
    const int pbase = blk * EPB;

    // ---- prologue: ALL ids for this lane's edge slot, all 5 tiles ----
    int e5[TILES], row5[TILES], col5[TILES];
#pragma unroll
    for (int tl = 0; tl < TILES; tl++) {
        int p = pbase + tl * 64 + ep;
        e5[tl] = csr[p];
        row5[tl] = rowpos[p];
    }
#pragma unroll
    for (int tl = 0; tl < TILES; tl++) col5[tl] = ei[NE + e5[tl]];

    // radial for all tiles (seg==0 lanes only; latency amortized across whole kernel)
    float rad5[TILES];
    if (seg == 0) {
#pragma unroll
        for (int tl = 0; tl < TILES; tl++) {
            float dx = coord[row5[tl] * 3 + 0] - coord[col5[tl] * 3 + 0];
            float dy = coord[row5[tl] * 3 + 1] - coord[col5[tl] * 3 + 1];
            float dz = coord[row5[tl] * 3 + 2] - coord[col5[tl] * 3 + 2];
            rad5[tl] = dx * dx + dy * dy + dz * dz;
        }
    }

    // depth-2 gather pipeline: preA = tile tl&1==0 slot, preB = tl&1==1 slot
    uint4 preA[4], preB[4];
    {
        int nd0 = (seg < 2) ? row5[0] : col5[0];
        const uint4* s0 = (const uint4*)(hb + (size_t)nd0 * 64 + (seg & 1) * 32);
#pragma unroll
        for (int c = 0; c < 4; c++) preA[c] = s0[c];
        int nd1 = (seg < 2) ? row5[1] : col5[1];
        const uint4* s1 = (const uint4*)(hb + (size_t)nd1 * 64 + (seg & 1) * 32);
#pragma unroll
        for (int c = 0; c < 4; c++) preB[c] = s1[c];
    }

#pragma unroll
    for (int tl = 0; tl < TILES; tl++) {
        uint4* P = (tl & 1) ? preB : preA;    // tl is compile-time constant (full unroll)
        if (tl > 0) __syncthreads();          // prev tile's Alds reads done
        // ---- stage current tile ----
#pragma unroll
        for (int c = 0; c < 4; c++)
            *(uint4*)(abase + ((rbase + c * 16) ^ sw)) = P[c];
        if (seg == 0) rad_lds[ep] = rad5[tl];
        if (seg == 1) rl_lds[ep] = row5[tl];
        if (seg == 2) el_lds[ep] = e5[tl];
        // ---- issue gather for tile tl+2 into the buffer just consumed ----
        if (tl + 2 < TILES) {
            int nd = (seg < 2) ? row5[tl + 2] : col5[tl + 2];
            const uint4* s = (const uint4*)(hb + (size_t)nd * 64 + (seg & 1) * 32);
#pragma unroll
            for (int c = 0; c < 4; c++) P[c] = s[c];
        }
        __syncthreads();                      // A + rad + rl + el ready

        // ---- layer 1 ----
        f32x4 acc[4];
#pragma unroll
        for (int rt = 0; rt < 4; rt++) {
#pragma unroll
            for (int r = 0; r < 4; r++)
                acc[rt][r] = fmaf(rad_lds[rt * 16 + hi * 4 + r], wl1, bj1);
        }
#pragma unroll
        for (int kc = 0; kc < 4; kc++) {
#pragma unroll
            for (int rt = 0; rt < 4; rt++) {
                int row = rt * 16 + lo;
                bf16x8 a = *(bf16x8*)(abase + ((row * 256 + kc * 64 + hi * 16) ^ ((row & 7) << 4)));
                acc[rt] = __builtin_amdgcn_mfma_f32_16x16x32_bf16(a, b1f[kc], acc[rt], 0, 0, 0);
            }
        }
#pragma unroll
        for (int rt = 0; rt < 4; rt++) {
#pragma unroll
            for (int r = 0; r < 4; r++) {
                int row = rt * 16 + hi * 4 + r;
                *(unsigned short*)(mbase + ((row * 128 + (wv * 16 + lo) * 2) ^ ((row & 7) << 4))) =
                    f2bf(lrelu(acc[rt][r]));
            }
        }
        __syncthreads();                      // M ready; Alds reads done

        // ---- layer 2 ----
        f32x4 acc2[4];
#pragma unroll
        for (int rt = 0; rt < 4; rt++) {
#pragma unroll
            for (int r = 0; r < 4; r++) acc2[rt][r] = bj2;
        }
#pragma unroll
        for (int kc = 0; kc < 2; kc++) {
#pragma unroll
            for (int rt = 0; rt < 4; rt++) {
                int row = rt * 16 + lo;
                bf16x8 a = *(bf16x8*)(mbase + ((row * 128 + kc * 64 + hi * 16) ^ ((row & 7) << 4)));
                acc2[rt] = __builtin_amdgcn_mfma_f32_16x16x32_bf16(a, b2f[kc], acc2[rt], 0, 0, 0);
            }
        }
        // lrelu -> fp32 out-tile in Alds (swizzled)
#pragma unroll
        for (int rt = 0; rt < 4; rt++) {
#pragma unroll
            for (int r = 0; r < 4; r++) {
                int row = rt * 16 + hi * 4 + r;
                *(float*)(abase + ((row * 256 + (wv * 16 + lo) * 4) ^ ((row & 7) << 4))) =
                    lrelu(acc2[rt][r]);
            }
        }
        __syncthreads();                      // out-tile ready

        // (a) edge_feat stores: wave wv -> rows [wv*16,+16); each instruction writes
        //     4 full 256B rows with lane-contiguous addresses (lanes 0-15 = one row)
        {
            int erow4 = lane >> 4;            // 0..3: row within group of 4
            int ch = lane & 15;               // 16B chunk within row
#pragma unroll
            for (int o = 0; o < 4; o++) {
                int ridx = wv * 16 + o * 4 + erow4;
                int ee = el_lds[ridx];
                uint4 v = *(uint4*)(abase + ((ridx * 256 + ch * 16) ^ ((ridx & 7) << 4)));
                *(uint4*)(edge_feat + (size_t)ee * 64 + ch * 4) = v;
            }
        }
        // (b) partial agg: wave wv scans pos window [wv*16,+16), lane = column
        {
            int i0 = wv * 16;
            int cur = rl_lds[i0];
            float s = *(float*)(abase + ((i0 * 256 + lane * 4) ^ ((i0 & 7) << 4)));
#pragma unroll
            for (int ii = 1; ii < 16; ii++) {
                int idx = i0 + ii;
                int r = rl_lds[idx];                 // wave-uniform
                float v = *(float*)(abase + ((idx * 256 + lane * 4) ^ ((idx & 7) << 4)));
                if (r != cur) {
                    atomicAdd(&agg[(size_t)cur * 64 + lane], s);
                    s = v; cur = r;
                } else {
                    s += v;
                }
            }
            atomicAdd(&agg[(size_t)cur * 64 + lane], s);
        }
    }
}

// ---------- node MLP (MFMA): streamed agg read, no gather ----------
__global__ __launch_bounds__(256) void agg_node_mfma(
    const unsigned short* __restrict__ hb, const float* __restrict__ h,
    const float* __restrict__ coord, const float* __restrict__ agg,
    const unsigned short* __restrict__ w1nt, const float* __restrict__ b1n,
    const unsigned short* __restrict__ w2nt, const float* __restrict__ b2n,
    float* __restrict__ h_out, float* __restrict__ coord_out)
{
    __shared__ unsigned short Alds[64 * 128];   // [hb | agg_bf16], swizzled
    __shared__ unsigned short Mlds[64 * 64];

    const int t = threadIdx.x, blk = blockIdx.x;
    const int lane = t & 63, wv = t >> 6;
    const int lo = lane & 15, hi = lane >> 4;
    const int nb = blk * 64;
    char* abase = (char*)Alds;
    char* mbase = (char*)Mlds;

    bf16x8 b1f[4], b2f[2];
#pragma unroll
    for (int kc = 0; kc < 4; kc++)
        b1f[kc] = *(const bf16x8*)(w1nt + (wv * 16 + lo) * 128 + kc * 32 + hi * 8);
#pragma unroll
    for (int kc = 0; kc < 2; kc++)
        b2f[kc] = *(const bf16x8*)(w2nt + (wv * 16 + lo) * 64 + kc * 32 + hi * 8);
    const float bj1 = b1n[wv * 16 + lo];
    const float bj2 = b2n[wv * 16 + lo];

    {   // stage hb rows -> A cols 0..63
        int row = t >> 2, seg = t & 3;
        int n = min(nb + row, NN - 1);
        const uint4* src = (const uint4*)(hb + (size_t)n * 64 + seg * 16);
        int base = row * 256 + seg * 32;
        int swr = (row & 7) << 4;
        uint4 v0 = src[0], v1 = src[1];
        *(uint4*)(abase + (base ^ swr)) = v0;
        *(uint4*)(abase + ((base + 16) ^ swr)) = v1;
    }
    {   // stage agg rows (fp32 -> bf16) -> A cols 64..127
        int row = t >> 2, seg = t & 3;
        int n = min(nb + row, NN - 1);
        const float4* asrc = (const float4*)(agg + (size_t)n * 64 + seg * 16);
        float4 a0 = asrc[0], a1 = asrc[1], a2 = asrc[2], a3 = asrc[3];
        unsigned int u0 = f2bf(a0.x) | ((unsigned)f2bf(a0.y) << 16);
        unsigned int u1 = f2bf(a0.z) | ((unsigned)f2bf(a0.w) << 16);
        unsigned int u2 = f2bf(a1.x) | ((unsigned)f2bf(a1.y) << 16);
        unsigned int u3 = f2bf(a1.z) | ((unsigned)f2bf(a1.w) << 16);
        unsigned int u4 = f2bf(a2.x) | ((unsigned)f2bf(a2.y) << 16);
        unsigned int u5 = f2bf(a2.z) | ((unsigned)f2bf(a2.w) << 16);
        unsigned int u6 = f2bf(a3.x) | ((unsigned)f2bf(a3.y) << 16);
        unsigned int u7 = f2bf(a3.z) | ((unsigned)f2bf(a3.w) << 16);
        int base = row * 256 + 128 + seg * 32;
        int swr = (row & 7) << 4;
        *(uint4*)(abase + (base ^ swr)) = make_uint4(u0, u1, u2, u3);
        *(uint4*)(abase + ((base + 16) ^ swr)) = make_uint4(u4, u5, u6, u7);
    }
    __syncthreads();

    f32x4 acc[4];
#pragma unroll
    for (int rt = 0; rt < 4; rt++) {
#pragma unroll
        for (int r = 0; r < 4; r++) acc[rt][r] = bj1;
    }
#pragma unroll
    for (int kc = 0; kc < 4; kc++) {
#pragma unroll
        for (int rt = 0; rt < 4; rt++) {
            int row = rt * 16 + lo;
            bf16x8 a = *(bf16x8*)(abase + ((row * 256 + kc * 64 + hi * 16) ^ ((row & 7) << 4)));
            acc[rt] = __builtin_amdgcn_mfma_f32_16x16x32_bf16(a, b1f[kc], acc[rt], 0, 0, 0);
        }
    }
#pragma unroll
    for (int rt = 0; rt < 4; rt++) {
#pragma unroll
        for (int r = 0; r < 4; r++) {
            int row = rt * 16 + hi * 4 + r;
            *(unsigned short*)(mbase + ((row * 128 + (wv * 16 + lo) * 2) ^ ((row & 7) << 4))) =
                f2bf(lrelu(acc[rt][r]));
        }
    }
    __syncthreads();

    f32x4 acc2[4];
#pragma unroll
    for (int rt = 0; rt < 4; rt++) {
#pragma unroll
        for (int r = 0; r < 4; r++) acc2[rt][r] = bj2;
    }
#pragma unroll
    for (int kc = 0; kc < 2; kc++) {
#pragma unroll
        for (int rt = 0; rt < 4; rt++) {
            int row = rt * 16 + lo;
            bf16x8 a = *(bf16x8*)(mbase + ((row * 128 + kc * 64 + hi * 16) ^ ((row & 7) << 4)));
            acc2[rt] = __builtin_amdgcn_mfma_f32_16x16x32_bf16(a, b2f[kc], acc2[rt], 0, 0, 0);
        }
    }
#pragma unroll
    for (int rt = 0; rt < 4; rt++) {
#pragma unroll
        for (int r = 0; r < 4; r++) {
            int row = rt * 16 + hi * 4 + r;
            int n = nb + row;
            if (n < NN) {
                int c = wv * 16 + lo;
                h_out[(size_t)n * 64 + c] = h[(size_t)n * 64 + c] + acc2[rt][r];
            }
        }
    }

    if (t < 192) {
        int idx = nb * 3 + t;
        if (idx < NN * 3) coord_out[idx] = coord[idx];
    }
}

extern "C" void kernel_launch(void* const* d_in, const int* in_sizes, int n_in,
                              void* d_out, int out_size, void* d_ws, size_t ws_size,
                              hipStream_t stream)
{
    const float* h     = (const float*)d_in[0];
    const float* coord = (const float*)d_in[1];
    const int*   ei    = (const int*)d_in[2];
    const float* w1e   = (const float*)d_in[3];
    const float* b1e   = (const float*)d_in[4];
    const float* w2e   = (const float*)d_in[5];
    const float* b2e   = (const float*)d_in[6];
    const float* w1n   = (const float*)d_in[7];
    const float* b1n   = (const float*)d_in[8];
    const float* w2n   = (const float*)d_in[9];
    const float* b2n   = (const float*)d_in[10];

    float* out       = (float*)d_out;
    float* h_out     = out;                         // [N, 64]
    float* coord_out = out + (size_t)NN * D;        // [N, 3]
    float* edge_feat = coord_out + (size_t)NN * 3;  // [E, 64]

    char* ws = (char*)d_ws;
    unsigned short* hb   = (unsigned short*)ws;  ws += sizeof(unsigned short) * (size_t)NN * D;  // 6.4 MB
    unsigned short* w1t  = (unsigned short*)ws;  ws += sizeof(unsigned short) * 64 * 128;
    unsigned short* w2t  = (unsigned short*)ws;  ws += sizeof(unsigned short) * 64 * 64;
    unsigned short* w1nt = (unsigned short*)ws;  ws += sizeof(unsigned short) * 64 * 128;
    unsigned short* w2nt = (unsigned short*)ws;  ws += sizeof(unsigned short) * 64 * 64;
    float* agg  = (float*)ws;                    ws += sizeof(float) * (size_t)NN * D;           // 12.8 MB
    int* counts = (int*)ws;                      ws += sizeof(int) * NN;
    int* offs   = (int*)ws;                      ws += sizeof(int) * NN;
    int* cursor = (int*)ws;                      ws += sizeof(int) * NN;
    int* bsums  = (int*)ws;                      ws += sizeof(int) * 64;
    int* csr    = (int*)ws;                      ws += sizeof(int) * NE;                         // 3.2 MB
    int* rowpos = (int*)ws;                      ws += sizeof(int) * NE;                         // 3.2 MB

    hipMemsetAsync(counts, 0, sizeof(int) * NN, stream);
    hipMemsetAsync(agg, 0, sizeof(float) * (size_t)NN * D, stream);

    prep_count<<<NE / 256, 256, 0, stream>>>(h, hb, ei, counts,
                                             w1e, w2e, w1n, w2n, w1t, w2t, w1nt, w2nt);

    scan_block_kernel<<<NB, SCAN_B, 0, stream>>>(counts, offs, bsums);
    scan_top_kernel<<<1, 64, 0, stream>>>(bsums);
    add_back_kernel<<<NB, SCAN_B, 0, stream>>>(offs, bsums, cursor);
    scatter_kernel<<<(NE + 255) / 256, 256, 0, stream>>>(ei, cursor, csr, rowpos);

    egnn_edge_mfma<<<NE / EPB, 256, 0, stream>>>(
        hb, coord, ei, csr, rowpos, w1t, b1e, w1e, w2t, b2e, edge_feat, agg);

    agg_node_mfma<<<(NN + 63) / 64, 256, 0, stream>>>(
        hb, h, coord, agg, w1nt, b1n, w2nt, b2n, h_out, coord_out);
}

// Round 11
// 238.324 us; speedup vs baseline: 2.0213x; 1.0795x over previous
//
#include <hip/hip_runtime.h>

#define NN 50000
#define NE 800000
#define D 64
#define SCAN_B 1024
#define NB ((NN + SCAN_B - 1) / SCAN_B)   // 49 scan blocks
#define TILES 5
#define EPB (64 * TILES)                   // 320 edges/block, grid 2500 exact

typedef __attribute__((ext_vector_type(8))) short bf16x8;
typedef __attribute__((ext_vector_type(4))) float f32x4;
typedef __attribute__((ext_vector_type(4))) unsigned int u32x4;

__device__ __forceinline__ float lrelu(float x) { return x >= 0.0f ? x : 0.2f * x; }

__device__ __forceinline__ unsigned short f2bf(float f) {
    unsigned int x = __float_as_uint(f);
    unsigned int r = (x + 0x7fffu + ((x >> 16) & 1u)) >> 16;   // RNE
    return (unsigned short)r;
}

// ---------- fused prep: h->bf16, all 4 weights ->bf16^T, degree count ----------
__global__ __launch_bounds__(256) void prep_count(const float* __restrict__ h,
                                                  unsigned short* __restrict__ hb,
                                                  const int* __restrict__ ei,
                                                  int* __restrict__ counts,
                                                  const float* __restrict__ w1e,
                                                  const float* __restrict__ w2e,
                                                  const float* __restrict__ w1n,
                                                  const float* __restrict__ w2n,
                                                  unsigned short* __restrict__ w1t,
                                                  unsigned short* __restrict__ w2t,
                                                  unsigned short* __restrict__ w1nt,
                                                  unsigned short* __restrict__ w2nt)
{
    int i = blockIdx.x * 256 + threadIdx.x;   // 800000 threads exactly
    float4 v = ((const float4*)h)[i];         // NN*16 == NE exactly
    ushort4 o;
    o.x = f2bf(v.x); o.y = f2bf(v.y); o.z = f2bf(v.z); o.w = f2bf(v.w);
    ((ushort4*)hb)[i] = o;
    atomicAdd(&counts[ei[i]], 1);
    if (i < 8192) {                            // w1t[j][k] = w1e[k][j]
        int j = i >> 7, k = i & 127;
        w1t[i] = f2bf(w1e[k * 64 + j]);
    } else if (i < 12288) {                    // w2t[j][k] = w2e[k][j]
        int t2 = i - 8192;
        int j = t2 >> 6, k = t2 & 63;
        w2t[t2] = f2bf(w2e[k * 64 + j]);
    } else if (i < 20480) {                    // w1nt[j][k] = w1n[k][j]
        int t3 = i - 12288;
        int j = t3 >> 7, k = t3 & 127;
        w1nt[t3] = f2bf(w1n[k * 64 + j]);
    } else if (i < 24576) {                    // w2nt[j][k] = w2n[k][j]
        int t4 = i - 20480;
        int j = t4 >> 6, k = t4 & 63;
        w2nt[t4] = f2bf(w2n[k * 64 + j]);
    }
}

// ---------- CSR build ----------
__global__ __launch_bounds__(SCAN_B) void scan_block_kernel(const int* __restrict__ counts,
                                                            int* __restrict__ offs,
                                                            int* __restrict__ bsums)
{
    int i = blockIdx.x * SCAN_B + threadIdx.x;
    int v = (i < NN) ? counts[i] : 0;
    int lane = threadIdx.x & 63;
    int wid = threadIdx.x >> 6;
    int x = v;
#pragma unroll
    for (int d = 1; d < 64; d <<= 1) {
        int y = __shfl_up(x, d);
        if (lane >= d) x += y;
    }
    __shared__ int wsum[16];
    if (lane == 63) wsum[wid] = x;
    __syncthreads();
    if (wid == 0) {
        int s = (lane < 16) ? wsum[lane] : 0;
#pragma unroll
        for (int d = 1; d < 16; d <<= 1) {
            int y = __shfl_up(s, d);
            if (lane >= d) s += y;
        }
        if (lane < 16) wsum[lane] = s;
    }
    __syncthreads();
    int woff = (wid == 0) ? 0 : wsum[wid - 1];
    int excl = woff + x - v;
    if (i < NN) offs[i] = excl;
    if (threadIdx.x == 0) bsums[blockIdx.x] = wsum[15];
}

__global__ void scan_top_kernel(int* __restrict__ bsums)
{
    if (threadIdx.x == 0 && blockIdx.x == 0) {
        int run = 0;
        for (int b = 0; b < NB; b++) { int t = bsums[b]; bsums[b] = run; run += t; }
    }
}

__global__ __launch_bounds__(SCAN_B) void add_back_kernel(int* __restrict__ offs,
                                                          const int* __restrict__ bsums,
                                                          int* __restrict__ cursor)
{
    int i = blockIdx.x * SCAN_B + threadIdx.x;
    if (i < NN) {
        int o = offs[i] + bsums[blockIdx.x];
        offs[i] = o;
        cursor[i] = o;
    }
}

__global__ __launch_bounds__(256) void scatter_kernel(const int* __restrict__ ei,
                                                      int* __restrict__ cursor,
                                                      int* __restrict__ csr,
                                                      int* __restrict__ rowpos,
                                                      int* __restrict__ colv)
{
    int e = blockIdx.x * 256 + threadIdx.x;
    if (e < NE) {
        int r = ei[e];
        int pos = atomicAdd(&cursor[r], 1);
        csr[pos] = e;
        rowpos[pos] = r;
        colv[pos] = ei[NE + e];
    }
}

// ---------- edge MLP: 4-wave cooperative, depth-2 pipeline, CSR order, fused agg ----------
// pos p = blk*EPB + tl*64 + ep; edge e = csr[p]; row = rowpos[p] (nondecreasing), col = colv[p].
// Wave wv owns output col-stripe [wv*16,+16). All index/coord chains hoisted to prologue.
// edge_feat written via nontemporal stores (write-only buffer, bypass L2 residency).
__global__ __launch_bounds__(256) void egnn_edge_mfma(
    const unsigned short* __restrict__ hb, const float* __restrict__ coord,
    const int* __restrict__ csr, const int* __restrict__ rowpos,
    const int* __restrict__ colv,
    const unsigned short* __restrict__ w1t, const float* __restrict__ b1e,
    const float* __restrict__ w1e,   // fp32, for radial row w1e[128][j]
    const unsigned short* __restrict__ w2t, const float* __restrict__ b2e,
    float* __restrict__ edge_feat, float* __restrict__ agg)
{
    __shared__ unsigned short Alds[64 * 128];   // 16 KB: A bf16 tile, then fp32 out overlay
    __shared__ unsigned short Mlds[64 * 64];    // 8 KB
    __shared__ float rad_lds[64];
    __shared__ int rl_lds[64];                  // row id per pos-slot
    __shared__ int el_lds[64];                  // edge id per pos-slot

    const int t = threadIdx.x;
    // bijective XCD swizzle (m204): nwg = 2500 = 8*312 + 4 -> q=312, rrem=4
    const int orig = blockIdx.x;
    const int xcd = orig & 7, idx8 = orig >> 3;
    const int blk = (xcd < 4 ? xcd * 313 : 4 * 313 + (xcd - 4) * 312) + idx8;

    const int lane = t & 63, wv = t >> 6;
    const int lo = lane & 15, hi = lane >> 4;

    // per-wave B stripes (24 VGPR resident)
    bf16x8 b1f[4], b2f[2];
#pragma unroll
    for (int kc = 0; kc < 4; kc++)
        b1f[kc] = *(const bf16x8*)(w1t + (wv * 16 + lo) * 128 + kc * 32 + hi * 8);
#pragma unroll
    for (int kc = 0; kc < 2; kc++)
        b2f[kc] = *(const bf16x8*)(w2t + (wv * 16 + lo) * 64 + kc * 32 + hi * 8);
    const float bj1 = b1e[wv * 16 + lo];
    const float wl1 = w1e[128 * 64 + wv * 16 + lo];
    const float bj2 = b2e[wv * 16 + lo];

    const int ep = t >> 2, seg = t & 3;   // staging: 4 threads per edge slot
    char* abase = (char*)Alds;
    char* mbase = (char*)Mlds;
    const int sw = (ep & 7) << 4;
    const int rbase = ep * 256 + seg * 64;
    const int pbase = blk * EPB;

    // ---- prologue: ALL ids for this lane's edge slot, all 5 tiles (sequential reads) ----
    int e5[TILES], row5[TILES], col5[TILES];
#pragma unroll
    for (int tl = 0; tl < TILES; tl++) {
        int p = pbase + tl * 64 + ep;
        e5[tl] = csr[p];
        row5[tl] = rowpos[p];
        col5[tl] = colv[p];
    }

    // radial for all tiles (seg==0 lanes only; latency amortized across whole kernel)
    float rad5[TILES];
    if (seg == 0) {
#pragma unroll
        for (int tl = 0; tl < TILES; tl++) {
            float dx = coord[row5[tl] * 3 + 0] - coord[col5[tl] * 3 + 0];
            float dy = coord[row5[tl] * 3 + 1] - coord[col5[tl] * 3 + 1];
            float dz = coord[row5[tl] * 3 + 2] - coord[col5[tl] * 3 + 2];
            rad5[tl] = dx * dx + dy * dy + dz * dz;
        }
    }

    // depth-2 gather pipeline: preA = even tiles, preB = odd tiles
    uint4 preA[4], preB[4];
    {
        int nd0 = (seg < 2) ? row5[0] : col5[0];
        const uint4* s0 = (const uint4*)(hb + (size_t)nd0 * 64 + (seg & 1) * 32);
#pragma unroll
        for (int c = 0; c < 4; c++) preA[c] = s0[c];
        int nd1 = (seg < 2) ? row5[1] : col5[1];
        const uint4* s1 = (const uint4*)(hb + (size_t)nd1 * 64 + (seg & 1) * 32);
#pragma unroll
        for (int c = 0; c < 4; c++) preB[c] = s1[c];
    }

#pragma unroll
    for (int tl = 0; tl < TILES; tl++) {
        uint4* P = (tl & 1) ? preB : preA;    // tl is compile-time constant (full unroll)
        if (tl > 0) __syncthreads();          // prev tile's Alds reads done
        // ---- stage current tile ----
#pragma unroll
        for (int c = 0; c < 4; c++)
            *(uint4*)(abase + ((rbase + c * 16) ^ sw)) = P[c];
        if (seg == 0) rad_lds[ep] = rad5[tl];
        if (seg == 1) rl_lds[ep] = row5[tl];
        if (seg == 2) el_lds[ep] = e5[tl];
        // ---- issue gather for tile tl+2 into the buffer just consumed ----
        if (tl + 2 < TILES) {
            int nd = (seg < 2) ? row5[tl + 2] : col5[tl + 2];
            const uint4* s = (const uint4*)(hb + (size_t)nd * 64 + (seg & 1) * 32);
#pragma unroll
            for (int c = 0; c < 4; c++) P[c] = s[c];
        }
        __syncthreads();                      // A + rad + rl + el ready

        // ---- layer 1 ----
        f32x4 acc[4];
#pragma unroll
        for (int rt = 0; rt < 4; rt++) {
#pragma unroll
            for (int r = 0; r < 4; r++)
                acc[rt][r] = fmaf(rad_lds[rt * 16 + hi * 4 + r], wl1, bj1);
        }
#pragma unroll
        for (int kc = 0; kc < 4; kc++) {
#pragma unroll
            for (int rt = 0; rt < 4; rt++) {
                int row = rt * 16 + lo;
                bf16x8 a = *(bf16x8*)(abase + ((row * 256 + kc * 64 + hi * 16) ^ ((row & 7) << 4)));
                acc[rt] = __builtin_amdgcn_mfma_f32_16x16x32_bf16(a, b1f[kc], acc[rt], 0, 0, 0);
            }
        }
#pragma unroll
        for (int rt = 0; rt < 4; rt++) {
#pragma unroll
            for (int r = 0; r < 4; r++) {
                int row = rt * 16 + hi * 4 + r;
                *(unsigned short*)(mbase + ((row * 128 + (wv * 16 + lo) * 2) ^ ((row & 7) << 4))) =
                    f2bf(lrelu(acc[rt][r]));
            }
        }
        __syncthreads();                      // M ready; Alds reads done

        // ---- layer 2 ----
        f32x4 acc2[4];
#pragma unroll
        for (int rt = 0; rt < 4; rt++) {
#pragma unroll
            for (int r = 0; r < 4; r++) acc2[rt][r] = bj2;
        }
#pragma unroll
        for (int kc = 0; kc < 2; kc++) {
#pragma unroll
            for (int rt = 0; rt < 4; rt++) {
                int row = rt * 16 + lo;
                bf16x8 a = *(bf16x8*)(mbase + ((row * 128 + kc * 64 + hi * 16) ^ ((row & 7) << 4)));
                acc2[rt] = __builtin_amdgcn_mfma_f32_16x16x32_bf16(a, b2f[kc], acc2[rt], 0, 0, 0);
            }
        }
        // lrelu -> fp32 out-tile in Alds (swizzled)
#pragma unroll
        for (int rt = 0; rt < 4; rt++) {
#pragma unroll
            for (int r = 0; r < 4; r++) {
                int row = rt * 16 + hi * 4 + r;
                *(float*)(abase + ((row * 256 + (wv * 16 + lo) * 4) ^ ((row & 7) << 4))) =
                    lrelu(acc2[rt][r]);
            }
        }
        __syncthreads();                      // out-tile ready

        // (a) edge_feat stores: nontemporal, full 256B rows, lane-contiguous
        {
            int erow4 = lane >> 4;            // 0..3: row within group of 4
            int ch = lane & 15;               // 16B chunk within row
#pragma unroll
            for (int o = 0; o < 4; o++) {
                int ridx = wv * 16 + o * 4 + erow4;
                int ee = el_lds[ridx];
                u32x4 v = *(u32x4*)(abase + ((ridx * 256 + ch * 16) ^ ((ridx & 7) << 4)));
                __builtin_nontemporal_store(v, (u32x4*)(edge_feat + (size_t)ee * 64 + ch * 4));
            }
        }
        // (b) partial agg: wave wv scans pos window [wv*16,+16), lane = column
        {
            int i0 = wv * 16;
            int cur = rl_lds[i0];
            float s = *(float*)(abase + ((i0 * 256 + lane * 4) ^ ((i0 & 7) << 4)));
#pragma unroll
            for (int ii = 1; ii < 16; ii++) {
                int idx = i0 + ii;
                int r = rl_lds[idx];                 // wave-uniform
                float v = *(float*)(abase + ((idx * 256 + lane * 4) ^ ((idx & 7) << 4)));
                if (r != cur) {
                    atomicAdd(&agg[(size_t)cur * 64 + lane], s);
                    s = v; cur = r;
                } else {
                    s += v;
                }
            }
            atomicAdd(&agg[(size_t)cur * 64 + lane], s);
        }
    }
}

// ---------- node MLP (MFMA): streamed agg read, no gather ----------
__global__ __launch_bounds__(256) void agg_node_mfma(
    const unsigned short* __restrict__ hb, const float* __restrict__ h,
    const float* __restrict__ coord, const float* __restrict__ agg,
    const unsigned short* __restrict__ w1nt, const float* __restrict__ b1n,
    const unsigned short* __restrict__ w2nt, const float* __restrict__ b2n,
    float* __restrict__ h_out, float* __restrict__ coord_out)
{
    __shared__ unsigned short Alds[64 * 128];   // [hb | agg_bf16], swizzled
    __shared__ unsigned short Mlds[64 * 64];

    const int t = threadIdx.x, blk = blockIdx.x;
    const int lane = t & 63, wv = t >> 6;
    const int lo = lane & 15, hi = lane >> 4;
    const int nb = blk * 64;
    char* abase = (char*)Alds;
    char* mbase = (char*)Mlds;

    bf16x8 b1f[4], b2f[2];
#pragma unroll
    for (int kc = 0; kc < 4; kc++)
        b1f[kc] = *(const bf16x8*)(w1nt + (wv * 16 + lo) * 128 + kc * 32 + hi * 8);
#pragma unroll
    for (int kc = 0; kc < 2; kc++)
        b2f[kc] = *(const bf16x8*)(w2nt + (wv * 16 + lo) * 64 + kc * 32 + hi * 8);
    const float bj1 = b1n[wv * 16 + lo];
    const float bj2 = b2n[wv * 16 + lo];

    {   // stage hb rows -> A cols 0..63
        int row = t >> 2, seg = t & 3;
        int n = min(nb + row, NN - 1);
        const uint4* src = (const uint4*)(hb + (size_t)n * 64 + seg * 16);
        int base = row * 256 + seg * 32;
        int swr = (row & 7) << 4;
        uint4 v0 = src[0], v1 = src[1];
        *(uint4*)(abase + (base ^ swr)) = v0;
        *(uint4*)(abase + ((base + 16) ^ swr)) = v1;
    }
    {   // stage agg rows (fp32 -> bf16) -> A cols 64..127
        int row = t >> 2, seg = t & 3;
        int n = min(nb + row, NN - 1);
        const float4* asrc = (const float4*)(agg + (size_t)n * 64 + seg * 16);
        float4 a0 = asrc[0], a1 = asrc[1], a2 = asrc[2], a3 = asrc[3];
        unsigned int u0 = f2bf(a0.x) | ((unsigned)f2bf(a0.y) << 16);
        unsigned int u1 = f2bf(a0.z) | ((unsigned)f2bf(a0.w) << 16);
        unsigned int u2 = f2bf(a1.x) | ((unsigned)f2bf(a1.y) << 16);
        unsigned int u3 = f2bf(a1.z) | ((unsigned)f2bf(a1.w) << 16);
        unsigned int u4 = f2bf(a2.x) | ((unsigned)f2bf(a2.y) << 16);
        unsigned int u5 = f2bf(a2.z) | ((unsigned)f2bf(a2.w) << 16);
        unsigned int u6 = f2bf(a3.x) | ((unsigned)f2bf(a3.y) << 16);
        unsigned int u7 = f2bf(a3.z) | ((unsigned)f2bf(a3.w) << 16);
        int base = row * 256 + 128 + seg * 32;
        int swr = (row & 7) << 4;
        *(uint4*)(abase + (base ^ swr)) = make_uint4(u0, u1, u2, u3);
        *(uint4*)(abase + ((base + 16) ^ swr)) = make_uint4(u4, u5, u6, u7);
    }
    __syncthreads();

    f32x4 acc[4];
#pragma unroll
    for (int rt = 0; rt < 4; rt++) {
#pragma unroll
        for (int r = 0; r < 4; r++) acc[rt][r] = bj1;
    }
#pragma unroll
    for (int kc = 0; kc < 4; kc++) {
#pragma unroll
        for (int rt = 0; rt < 4; rt++) {
            int row = rt * 16 + lo;
            bf16x8 a = *(bf16x8*)(abase + ((row * 256 + kc * 64 + hi * 16) ^ ((row & 7) << 4)));
            acc[rt] = __builtin_amdgcn_mfma_f32_16x16x32_bf16(a, b1f[kc], acc[rt], 0, 0, 0);
        }
    }
#pragma unroll
    for (int rt = 0; rt < 4; rt++) {
#pragma unroll
        for (int r = 0; r < 4; r++) {
            int row = rt * 16 + hi * 4 + r;
            *(unsigned short*)(mbase + ((row * 128 + (wv * 16 + lo) * 2) ^ ((row & 7) << 4))) =
                f2bf(lrelu(acc[rt][r]));
        }
    }
    __syncthreads();

    f32x4 acc2[4];
#pragma unroll
    for (int rt = 0; rt < 4; rt++) {
#pragma unroll
        for (int r = 0; r < 4; r++) acc2[rt][r] = bj2;
    }
#pragma unroll
    for (int kc = 0; kc < 2; kc++) {
#pragma unroll
        for (int rt = 0; rt < 4; rt++) {
            int row = rt * 16 + lo;
            bf16x8 a = *(bf16x8*)(mbase + ((row * 128 + kc * 64 + hi * 16) ^ ((row & 7) << 4)));
            acc2[rt] = __builtin_amdgcn_mfma_f32_16x16x32_bf16(a, b2f[kc], acc2[rt], 0, 0, 0);
        }
    }
#pragma unroll
    for (int rt = 0; rt < 4; rt++) {
#pragma unroll
        for (int r = 0; r < 4; r++) {
            int row = rt * 16 + hi * 4 + r;
            int n = nb + row;
            if (n < NN) {
                int c = wv * 16 + lo;
                float v = h[(size_t)n * 64 + c] + acc2[rt][r];
                __builtin_nontemporal_store(v, h_out + (size_t)n * 64 + c);
            }
        }
    }

    if (t < 192) {
        int idx = nb * 3 + t;
        if (idx < NN * 3) coord_out[idx] = coord[idx];
    }
}

extern "C" void kernel_launch(void* const* d_in, const int* in_sizes, int n_in,
                              void* d_out, int out_size, void* d_ws, size_t ws_size,
                              hipStream_t stream)
{
    const float* h     = (const float*)d_in[0];
    const float* coord = (const float*)d_in[1];
    const int*   ei    = (const int*)d_in[2];
    const float* w1e   = (const float*)d_in[3];
    const float* b1e   = (const float*)d_in[4];
    const float* w2e   = (const float*)d_in[5];
    const float* b2e   = (const float*)d_in[6];
    const float* w1n   = (const float*)d_in[7];
    const float* b1n   = (const float*)d_in[8];
    const float* w2n   = (const float*)d_in[9];
    const float* b2n   = (const float*)d_in[10];

    float* out       = (float*)d_out;
    float* h_out     = out;                         // [N, 64]
    float* coord_out = out + (size_t)NN * D;        // [N, 3]
    float* edge_feat = coord_out + (size_t)NN * 3;  // [E, 64]

    char* ws = (char*)d_ws;
    unsigned short* hb   = (unsigned short*)ws;  ws += sizeof(unsigned short) * (size_t)NN * D;  // 6.4 MB
    unsigned short* w1t  = (unsigned short*)ws;  ws += sizeof(unsigned short) * 64 * 128;
    unsigned short* w2t  = (unsigned short*)ws;  ws += sizeof(unsigned short) * 64 * 64;
    unsigned short* w1nt = (unsigned short*)ws;  ws += sizeof(unsigned short) * 64 * 128;
    unsigned short* w2nt = (unsigned short*)ws;  ws += sizeof(unsigned short) * 64 * 64;
    float* agg  = (float*)ws;                    ws += sizeof(float) * (size_t)NN * D;           // 12.8 MB
    int* counts = (int*)ws;                      ws += sizeof(int) * NN;
    int* offs   = (int*)ws;                      ws += sizeof(int) * NN;
    int* cursor = (int*)ws;                      ws += sizeof(int) * NN;
    int* bsums  = (int*)ws;                      ws += sizeof(int) * 64;
    int* csr    = (int*)ws;                      ws += sizeof(int) * NE;                         // 3.2 MB
    int* rowpos = (int*)ws;                      ws += sizeof(int) * NE;                         // 3.2 MB
    int* colv   = (int*)ws;                      ws += sizeof(int) * NE;                         // 3.2 MB

    hipMemsetAsync(counts, 0, sizeof(int) * NN, stream);
    hipMemsetAsync(agg, 0, sizeof(float) * (size_t)NN * D, stream);

    prep_count<<<NE / 256, 256, 0, stream>>>(h, hb, ei, counts,
                                             w1e, w2e, w1n, w2n, w1t, w2t, w1nt, w2nt);

    scan_block_kernel<<<NB, SCAN_B, 0, stream>>>(counts, offs, bsums);
    scan_top_kernel<<<1, 64, 0, stream>>>(bsums);
    add_back_kernel<<<NB, SCAN_B, 0, stream>>>(offs, bsums, cursor);
    scatter_kernel<<<(NE + 255) / 256, 256, 0, stream>>>(ei, cursor, csr, rowpos, colv);

    egnn_edge_mfma<<<NE / EPB, 256, 0, stream>>>(
        hb, coord, csr, rowpos, colv, w1t, b1e, w1e, w2t, b2e, edge_feat, agg);

    agg_node_mfma<<<(NN + 63) / 64, 256, 0, stream>>>(
        hb, h, coord, agg, w1nt, b1n, w2nt, b2n, h_out, coord_out);
}

// Round 12
// 202.516 us; speedup vs baseline: 2.3787x; 1.1768x over previous
//
#include <hip/hip_runtime.h>

#define NN 50000
#define NE 800000
#define D 64
#define SCAN_B 1024
#define NB ((NN + SCAN_B - 1) / SCAN_B)   // 49 scan blocks
#define TILES 5
#define EPB (64 * TILES)                   // 320 edges/block (4 waves x 80), grid 2500

typedef __attribute__((ext_vector_type(8))) short bf16x8;
typedef __attribute__((ext_vector_type(4))) float f32x4;
typedef __attribute__((ext_vector_type(4))) unsigned int u32x4;

__device__ __forceinline__ float lrelu(float x) { return x >= 0.0f ? x : 0.2f * x; }

__device__ __forceinline__ unsigned short f2bf(float f) {
    unsigned int x = __float_as_uint(f);
    unsigned int r = (x + 0x7fffu + ((x >> 16) & 1u)) >> 16;   // RNE
    return (unsigned short)r;
}

// wave-local LDS fence (proven correct in R8): drain my LDS ops, pin scheduler
__device__ __forceinline__ void wave_lds_fence() {
    asm volatile("s_waitcnt lgkmcnt(0)" ::: "memory");
    __builtin_amdgcn_sched_barrier(0);
}

// ---------- fused prep: h->bf16, all 4 weights ->bf16^T, degree count ----------
__global__ __launch_bounds__(256) void prep_count(const float* __restrict__ h,
                                                  unsigned short* __restrict__ hb,
                                                  const int* __restrict__ ei,
                                                  int* __restrict__ counts,
                                                  const float* __restrict__ w1e,
                                                  const float* __restrict__ w2e,
                                                  const float* __restrict__ w1n,
                                                  const float* __restrict__ w2n,
                                                  unsigned short* __restrict__ w1t,
                                                  unsigned short* __restrict__ w2t,
                                                  unsigned short* __restrict__ w1nt,
                                                  unsigned short* __restrict__ w2nt)
{
    int i = blockIdx.x * 256 + threadIdx.x;   // 800000 threads exactly
    float4 v = ((const float4*)h)[i];         // NN*16 == NE exactly
    ushort4 o;
    o.x = f2bf(v.x); o.y = f2bf(v.y); o.z = f2bf(v.z); o.w = f2bf(v.w);
    ((ushort4*)hb)[i] = o;
    atomicAdd(&counts[ei[i]], 1);
    if (i < 8192) {                            // w1t[j][k] = w1e[k][j]
        int j = i >> 7, k = i & 127;
        w1t[i] = f2bf(w1e[k * 64 + j]);
    } else if (i < 12288) {                    // w2t[j][k] = w2e[k][j]
        int t2 = i - 8192;
        int j = t2 >> 6, k = t2 & 63;
        w2t[t2] = f2bf(w2e[k * 64 + j]);
    } else if (i < 20480) {                    // w1nt[j][k] = w1n[k][j]
        int t3 = i - 12288;
        int j = t3 >> 7, k = t3 & 127;
        w1nt[t3] = f2bf(w1n[k * 64 + j]);
    } else if (i < 24576) {                    // w2nt[j][k] = w2n[k][j]
        int t4 = i - 20480;
        int j = t4 >> 6, k = t4 & 63;
        w2nt[t4] = f2bf(w2n[k * 64 + j]);
    }
}

// ---------- CSR build ----------
__global__ __launch_bounds__(SCAN_B) void scan_block_kernel(const int* __restrict__ counts,
                                                            int* __restrict__ offs,
                                                            int* __restrict__ bsums)
{
    int i = blockIdx.x * SCAN_B + threadIdx.x;
    int v = (i < NN) ? counts[i] : 0;
    int lane = threadIdx.x & 63;
    int wid = threadIdx.x >> 6;
    int x = v;
#pragma unroll
    for (int d = 1; d < 64; d <<= 1) {
        int y = __shfl_up(x, d);
        if (lane >= d) x += y;
    }
    __shared__ int wsum[16];
    if (lane == 63) wsum[wid] = x;
    __syncthreads();
    if (wid == 0) {
        int s = (lane < 16) ? wsum[lane] : 0;
#pragma unroll
        for (int d = 1; d < 16; d <<= 1) {
            int y = __shfl_up(s, d);
            if (lane >= d) s += y;
        }
        if (lane < 16) wsum[lane] = s;
    }
    __syncthreads();
    int woff = (wid == 0) ? 0 : wsum[wid - 1];
    int excl = woff + x - v;
    if (i < NN) offs[i] = excl;
    if (threadIdx.x == 0) bsums[blockIdx.x] = wsum[15];
}

__global__ void scan_top_kernel(int* __restrict__ bsums)
{
    if (threadIdx.x == 0 && blockIdx.x == 0) {
        int run = 0;
        for (int b = 0; b < NB; b++) { int t = bsums[b]; bsums[b] = run; run += t; }
    }
}

__global__ __launch_bounds__(SCAN_B) void add_back_kernel(int* __restrict__ offs,
                                                          const int* __restrict__ bsums,
                                                          int* __restrict__ cursor)
{
    int i = blockIdx.x * SCAN_B + threadIdx.x;
    if (i < NN) {
        int o = offs[i] + bsums[blockIdx.x];
        offs[i] = o;
        cursor[i] = o;
    }
}

__global__ __launch_bounds__(256) void scatter_kernel(const int* __restrict__ ei,
                                                      int* __restrict__ cursor,
                                                      int* __restrict__ csr,
                                                      int* __restrict__ rowpos,
                                                      int* __restrict__ colv)
{
    int e = blockIdx.x * 256 + threadIdx.x;
    if (e < NE) {
        int r = ei[e];
        int pos = atomicAdd(&cursor[r], 1);
        csr[pos] = e;
        rowpos[pos] = r;
        colv[pos] = ei[NE + e];
    }
}

// ---------- edge MLP: wave-independent 16-edge tiles, weights in LDS, no in-loop barriers ----------
// Wave wv owns pos [blk*EPB + wv*80, +80) in 5 tiles of 16 (CSR order).
// Lane's edge slot = lane&15; A-fragments loaded directly from global (depth-2 prefetch).
// M (layer-1 out, bf16) and O (layer-2 out, fp32) live in wave-private LDS slices.
__global__ __launch_bounds__(256) void egnn_edge_mfma(
    const unsigned short* __restrict__ hb, const float* __restrict__ coord,
    const int* __restrict__ csr, const int* __restrict__ rowpos,
    const int* __restrict__ colv,
    const unsigned short* __restrict__ w1t, const float* __restrict__ b1e,
    const float* __restrict__ w1e,   // fp32, for radial row w1e[128][j]
    const unsigned short* __restrict__ w2t, const float* __restrict__ b2e,
    float* __restrict__ edge_feat, float* __restrict__ agg)
{
    __shared__ unsigned short W1[64 * 128];   // 16 KB, swizzled [j][k]
    __shared__ unsigned short W2[64 * 64];    // 8 KB, swizzled
    __shared__ unsigned short Mb[4][16 * 64]; // 8 KB, 2 KB/wave
    __shared__ float Ob[4][16 * 64];          // 16 KB, 4 KB/wave

    const int t = threadIdx.x;
    // bijective XCD swizzle (m204): nwg = 2500 = 8*312 + 4
    const int orig = blockIdx.x;
    const int xcd = orig & 7, idx8 = orig >> 3;
    const int blk = (xcd < 4 ? xcd * 313 : 4 * 313 + (xcd - 4) * 312) + idx8;

    const int lane = t & 63, wv = t >> 6;
    const int lo = lane & 15, hi = lane >> 4;

    // ---- stage swizzled weights into LDS (once) ----
    for (int c = t; c < 1024; c += 256) {              // W1: 1024 x 16B chunks
        int j = c >> 4, ci = c & 15;
        uint4 v = *(const uint4*)(w1t + j * 128 + ci * 8);
        *(uint4*)((char*)W1 + ((j * 256 + ci * 16) ^ ((j & 7) << 4))) = v;
    }
    for (int c = t; c < 512; c += 256) {               // W2: 512 x 16B chunks
        int j = c >> 3, ci = c & 7;
        uint4 v = *(const uint4*)(w2t + j * 64 + ci * 8);
        *(uint4*)((char*)W2 + ((j * 128 + ci * 16) ^ ((j & 7) << 4))) = v;
    }
    float bj1[4], wl1[4], bj2[4];
#pragma unroll
    for (int ct = 0; ct < 4; ct++) {
        bj1[ct] = b1e[ct * 16 + lo];
        wl1[ct] = w1e[128 * 64 + ct * 16 + lo];
        bj2[ct] = b2e[ct * 16 + lo];
    }
    __syncthreads();                                   // only barrier in the kernel

    char* w1b = (char*)W1;
    char* w2b = (char*)W2;
    char* mb = (char*)Mb[wv];
    char* ob = (char*)Ob[wv];

    const int pbase = blk * EPB + wv * (16 * TILES);

    // ---- ids: every lane holds its edge slot (lane&15) for all 5 tiles ----
    int e5[TILES], row5[TILES], col5[TILES];
    float rad5[TILES];
#pragma unroll
    for (int tl = 0; tl < TILES; tl++) {
        int p = pbase + tl * 16 + lo;     // 4-fold redundant across hi -> same-line coalesce
        e5[tl] = csr[p];
        row5[tl] = rowpos[p];
        col5[tl] = colv[p];
    }
#pragma unroll
    for (int tl = 0; tl < TILES; tl++) {
        float dx = coord[row5[tl] * 3 + 0] - coord[col5[tl] * 3 + 0];
        float dy = coord[row5[tl] * 3 + 1] - coord[col5[tl] * 3 + 1];
        float dz = coord[row5[tl] * 3 + 2] - coord[col5[tl] * 3 + 2];
        rad5[tl] = dx * dx + dy * dy + dz * dz;
    }

    // ---- A-fragment prefetch registers (16B each; row kc0/kc1, col kc0/kc1) ----
    uint4 aR0, aR1, aC0, aC1, nR0, nR1, nC0, nC1;
    aR0 = *(const uint4*)(hb + (size_t)row5[0] * 64 + hi * 8);
    aR1 = *(const uint4*)(hb + (size_t)row5[0] * 64 + 32 + hi * 8);
    aC0 = *(const uint4*)(hb + (size_t)col5[0] * 64 + hi * 8);
    aC1 = *(const uint4*)(hb + (size_t)col5[0] * 64 + 32 + hi * 8);

#pragma unroll
    for (int tl = 0; tl < TILES; tl++) {
        // issue next tile's A gathers (hidden under this tile's compute)
        if (tl + 1 < TILES) {
            nR0 = *(const uint4*)(hb + (size_t)row5[tl + 1] * 64 + hi * 8);
            nR1 = *(const uint4*)(hb + (size_t)row5[tl + 1] * 64 + 32 + hi * 8);
            nC0 = *(const uint4*)(hb + (size_t)col5[tl + 1] * 64 + hi * 8);
            nC1 = *(const uint4*)(hb + (size_t)col5[tl + 1] * 64 + 32 + hi * 8);
        }

        // ---- layer 1: acc init (bias + radial) then 16 MFMA, B from LDS ----
        float radr[4];
#pragma unroll
        for (int r = 0; r < 4; r++) radr[r] = __shfl(rad5[tl], hi * 4 + r);
        f32x4 acc[4];
#pragma unroll
        for (int ct = 0; ct < 4; ct++)
#pragma unroll
            for (int r = 0; r < 4; r++) acc[ct][r] = fmaf(radr[r], wl1[ct], bj1[ct]);

        bf16x8 af0 = *reinterpret_cast<bf16x8*>(&aR0);
        bf16x8 af1 = *reinterpret_cast<bf16x8*>(&aR1);
        bf16x8 af2 = *reinterpret_cast<bf16x8*>(&aC0);
        bf16x8 af3 = *reinterpret_cast<bf16x8*>(&aC1);
#pragma unroll
        for (int kc = 0; kc < 4; kc++) {
            bf16x8 a = (kc == 0) ? af0 : (kc == 1) ? af1 : (kc == 2) ? af2 : af3;
#pragma unroll
            for (int ct = 0; ct < 4; ct++) {
                bf16x8 b = *(bf16x8*)(w1b + (((ct * 16 + lo) * 256 + kc * 64 + hi * 16) ^ ((lo & 7) << 4)));
                acc[ct] = __builtin_amdgcn_mfma_f32_16x16x32_bf16(a, b, acc[ct], 0, 0, 0);
            }
        }

        // ---- M stage (wave-private), layer 2 ----
#pragma unroll
        for (int ct = 0; ct < 4; ct++)
#pragma unroll
            for (int r = 0; r < 4; r++) {
                int row = hi * 4 + r;
                *(unsigned short*)(mb + ((row * 128 + (ct * 16 + lo) * 2) ^ ((row & 7) << 4))) =
                    f2bf(lrelu(acc[ct][r]));
            }
        wave_lds_fence();

        f32x4 acc2[4];
#pragma unroll
        for (int ct = 0; ct < 4; ct++)
#pragma unroll
            for (int r = 0; r < 4; r++) acc2[ct][r] = bj2[ct];
#pragma unroll
        for (int kc = 0; kc < 2; kc++) {
            bf16x8 a2 = *(bf16x8*)(mb + ((lo * 128 + kc * 64 + hi * 16) ^ ((lo & 7) << 4)));
#pragma unroll
            for (int ct = 0; ct < 4; ct++) {
                bf16x8 b = *(bf16x8*)(w2b + (((ct * 16 + lo) * 128 + kc * 64 + hi * 16) ^ ((lo & 7) << 4)));
                acc2[ct] = __builtin_amdgcn_mfma_f32_16x16x32_bf16(a2, b, acc2[ct], 0, 0, 0);
            }
        }

        // ---- O stage (wave-private fp32), then stores + segmented agg scan ----
#pragma unroll
        for (int ct = 0; ct < 4; ct++)
#pragma unroll
            for (int r = 0; r < 4; r++) {
                int row = hi * 4 + r;
                *(float*)(ob + ((row * 256 + (ct * 16 + lo) * 4) ^ ((row & 7) << 4))) =
                    lrelu(acc2[ct][r]);
            }
        wave_lds_fence();

        // stores: quarter-wave per row, 4 full 256B rows per pass, nontemporal
#pragma unroll
        for (int o = 0; o < 4; o++) {
            int ridx = o * 4 + hi;
            int ee = __shfl(e5[tl], ridx);
            u32x4 v = *(u32x4*)(ob + ((ridx * 256 + lo * 16) ^ ((ridx & 7) << 4)));
            __builtin_nontemporal_store(v, (u32x4*)(edge_feat + (size_t)ee * 64 + lo * 4));
        }
        // segmented scan over this wave's 16 sorted pos (lane = column)
        {
            int cur = __shfl(row5[tl], 0);
            float s = *(float*)(ob + ((lane * 4) ^ 0));
#pragma unroll
            for (int ii = 1; ii < 16; ii++) {
                int r = __shfl(row5[tl], ii);
                float v = *(float*)(ob + ((ii * 256 + lane * 4) ^ ((ii & 7) << 4)));
                if (r != cur) {
                    atomicAdd(&agg[(size_t)cur * 64 + lane], s);
                    s = v; cur = r;
                } else {
                    s += v;
                }
            }
            atomicAdd(&agg[(size_t)cur * 64 + lane], s);
        }

        aR0 = nR0; aR1 = nR1; aC0 = nC0; aC1 = nC1;
    }
}

// ---------- node MLP (MFMA): streamed agg read, no gather ----------
__global__ __launch_bounds__(256) void agg_node_mfma(
    const unsigned short* __restrict__ hb, const float* __restrict__ h,
    const float* __restrict__ coord, const float* __restrict__ agg,
    const unsigned short* __restrict__ w1nt, const float* __restrict__ b1n,
    const unsigned short* __restrict__ w2nt, const float* __restrict__ b2n,
    float* __restrict__ h_out, float* __restrict__ coord_out)
{
    __shared__ unsigned short Alds[64 * 128];   // [hb | agg_bf16], swizzled
    __shared__ unsigned short Mlds[64 * 64];

    const int t = threadIdx.x, blk = blockIdx.x;
    const int lane = t & 63, wv = t >> 6;
    const int lo = lane & 15, hi = lane >> 4;
    const int nb = blk * 64;
    char* abase = (char*)Alds;
    char* mbase = (char*)Mlds;

    bf16x8 b1f[4], b2f[2];
#pragma unroll
    for (int kc = 0; kc < 4; kc++)
        b1f[kc] = *(const bf16x8*)(w1nt + (wv * 16 + lo) * 128 + kc * 32 + hi * 8);
#pragma unroll
    for (int kc = 0; kc < 2; kc++)
        b2f[kc] = *(const bf16x8*)(w2nt + (wv * 16 + lo) * 64 + kc * 32 + hi * 8);
    const float bj1 = b1n[wv * 16 + lo];
    const float bj2 = b2n[wv * 16 + lo];

    {   // stage hb rows -> A cols 0..63
        int row = t >> 2, seg = t & 3;
        int n = min(nb + row, NN - 1);
        const uint4* src = (const uint4*)(hb + (size_t)n * 64 + seg * 16);
        int base = row * 256 + seg * 32;
        int swr = (row & 7) << 4;
        uint4 v0 = src[0], v1 = src[1];
        *(uint4*)(abase + (base ^ swr)) = v0;
        *(uint4*)(abase + ((base + 16) ^ swr)) = v1;
    }
    {   // stage agg rows (fp32 -> bf16) -> A cols 64..127
        int row = t >> 2, seg = t & 3;
        int n = min(nb + row, NN - 1);
        const float4* asrc = (const float4*)(agg + (size_t)n * 64 + seg * 16);
        float4 a0 = asrc[0], a1 = asrc[1], a2 = asrc[2], a3 = asrc[3];
        unsigned int u0 = f2bf(a0.x) | ((unsigned)f2bf(a0.y) << 16);
        unsigned int u1 = f2bf(a0.z) | ((unsigned)f2bf(a0.w) << 16);
        unsigned int u2 = f2bf(a1.x) | ((unsigned)f2bf(a1.y) << 16);
        unsigned int u3 = f2bf(a1.z) | ((unsigned)f2bf(a1.w) << 16);
        unsigned int u4 = f2bf(a2.x) | ((unsigned)f2bf(a2.y) << 16);
        unsigned int u5 = f2bf(a2.z) | ((unsigned)f2bf(a2.w) << 16);
        unsigned int u6 = f2bf(a3.x) | ((unsigned)f2bf(a3.y) << 16);
        unsigned int u7 = f2bf(a3.z) | ((unsigned)f2bf(a3.w) << 16);
        int base = row * 256 + 128 + seg * 32;
        int swr = (row & 7) << 4;
        *(uint4*)(abase + (base ^ swr)) = make_uint4(u0, u1, u2, u3);
        *(uint4*)(abase + ((base + 16) ^ swr)) = make_uint4(u4, u5, u6, u7);
    }
    __syncthreads();

    f32x4 acc[4];
#pragma unroll
    for (int rt = 0; rt < 4; rt++) {
#pragma unroll
        for (int r = 0; r < 4; r++) acc[rt][r] = bj1;
    }
#pragma unroll
    for (int kc = 0; kc < 4; kc++) {
#pragma unroll
        for (int rt = 0; rt < 4; rt++) {
            int row = rt * 16 + lo;
            bf16x8 a = *(bf16x8*)(abase + ((row * 256 + kc * 64 + hi * 16) ^ ((row & 7) << 4)));
            acc[rt] = __builtin_amdgcn_mfma_f32_16x16x32_bf16(a, b1f[kc], acc[rt], 0, 0, 0);
        }
    }
#pragma unroll
    for (int rt = 0; rt < 4; rt++) {
#pragma unroll
        for (int r = 0; r < 4; r++) {
            int row = rt * 16 + hi * 4 + r;
            *(unsigned short*)(mbase + ((row * 128 + (wv * 16 + lo) * 2) ^ ((row & 7) << 4))) =
                f2bf(lrelu(acc[rt][r]));
        }
    }
    __syncthreads();

    f32x4 acc2[4];
#pragma unroll
    for (int rt = 0; rt < 4; rt++) {
#pragma unroll
        for (int r = 0; r < 4; r++) acc2[rt][r] = bj2;
    }
#pragma unroll
    for (int kc = 0; kc < 2; kc++) {
#pragma unroll
        for (int rt = 0; rt < 4; rt++) {
            int row = rt * 16 + lo;
            bf16x8 a = *(bf16x8*)(mbase + ((row * 128 + kc * 64 + hi * 16) ^ ((row & 7) << 4)));
            acc2[rt] = __builtin_amdgcn_mfma_f32_16x16x32_bf16(a, b2f[kc], acc2[rt], 0, 0, 0);
        }
    }
#pragma unroll
    for (int rt = 0; rt < 4; rt++) {
#pragma unroll
        for (int r = 0; r < 4; r++) {
            int row = rt * 16 + hi * 4 + r;
            int n = nb + row;
            if (n < NN) {
                int c = wv * 16 + lo;
                float v = h[(size_t)n * 64 + c] + acc2[rt][r];
                __builtin_nontemporal_store(v, h_out + (size_t)n * 64 + c);
            }
        }
    }

    if (t < 192) {
        int idx = nb * 3 + t;
        if (idx < NN * 3) coord_out[idx] = coord[idx];
    }
}

extern "C" void kernel_launch(void* const* d_in, const int* in_sizes, int n_in,
                              void* d_out, int out_size, void* d_ws, size_t ws_size,
                              hipStream_t stream)
{
    const float* h     = (const float*)d_in[0];
    const float* coord = (const float*)d_in[1];
    const int*   ei    = (const int*)d_in[2];
    const float* w1e   = (const float*)d_in[3];
    const float* b1e   = (const float*)d_in[4];
    const float* w2e   = (const float*)d_in[5];
    const float* b2e   = (const float*)d_in[6];
    const float* w1n   = (const float*)d_in[7];
    const float* b1n   = (const float*)d_in[8];
    const float* w2n   = (const float*)d_in[9];
    const float* b2n   = (const float*)d_in[10];

    float* out       = (float*)d_out;
    float* h_out     = out;                         // [N, 64]
    float* coord_out = out + (size_t)NN * D;        // [N, 3]
    float* edge_feat = coord_out + (size_t)NN * 3;  // [E, 64]

    char* ws = (char*)d_ws;
    unsigned short* hb   = (unsigned short*)ws;  ws += sizeof(unsigned short) * (size_t)NN * D;  // 6.4 MB
    unsigned short* w1t  = (unsigned short*)ws;  ws += sizeof(unsigned short) * 64 * 128;
    unsigned short* w2t  = (unsigned short*)ws;  ws += sizeof(unsigned short) * 64 * 64;
    unsigned short* w1nt = (unsigned short*)ws;  ws += sizeof(unsigned short) * 64 * 128;
    unsigned short* w2nt = (unsigned short*)ws;  ws += sizeof(unsigned short) * 64 * 64;
    float* agg  = (float*)ws;                    ws += sizeof(float) * (size_t)NN * D;           // 12.8 MB
    int* counts = (int*)ws;                      ws += sizeof(int) * NN;
    int* offs   = (int*)ws;                      ws += sizeof(int) * NN;
    int* cursor = (int*)ws;                      ws += sizeof(int) * NN;
    int* bsums  = (int*)ws;                      ws += sizeof(int) * 64;
    int* csr    = (int*)ws;                      ws += sizeof(int) * NE;                         // 3.2 MB
    int* rowpos = (int*)ws;                      ws += sizeof(int) * NE;                         // 3.2 MB
    int* colv   = (int*)ws;                      ws += sizeof(int) * NE;                         // 3.2 MB

    hipMemsetAsync(counts, 0, sizeof(int) * NN, stream);
    hipMemsetAsync(agg, 0, sizeof(float) * (size_t)NN * D, stream);

    prep_count<<<NE / 256, 256, 0, stream>>>(h, hb, ei, counts,
                                             w1e, w2e, w1n, w2n, w1t, w2t, w1nt, w2nt);

    scan_block_kernel<<<NB, SCAN_B, 0, stream>>>(counts, offs, bsums);
    scan_top_kernel<<<1, 64, 0, stream>>>(bsums);
    add_back_kernel<<<NB, SCAN_B, 0, stream>>>(offs, bsums, cursor);
    scatter_kernel<<<(NE + 255) / 256, 256, 0, stream>>>(ei, cursor, csr, rowpos, colv);

    egnn_edge_mfma<<<NE / EPB, 256, 0, stream>>>(
        hb, coord, csr, rowpos, colv, w1t, b1e, w1e, w2t, b2e, edge_feat, agg);

    agg_node_mfma<<<(NN + 63) / 64, 256, 0, stream>>>(
        hb, h, coord, agg, w1nt, b1n, w2nt, b2n, h_out, coord_out);
}